// Round 1
// baseline (109.871 us; speedup 1.0000x reference)
//
#include <hip/hip_runtime.h>
#include <math.h>

#define NPOS 512
#define DIM  512
#define NB   1024
#define EPSV 1e-5f
#define COS_EPS 1e-8f
#define ZSPLIT 4
#define KSLICE (DIM / ZSPLIT)   // 128

// ws float offsets
#define OFF_INV 0                      // [1024] inv norms, allv order [pos;neg]
#define OFF_T1  1024                   // [512]  pos . w1
#define OFF_T2  1536                   // [1024] allv . w2
#define OFF_P   2560                   // cos partials: ZSPLIT slices of [512*1024]
#define OFF_Q   (OFF_P + ZSPLIT * NPOS * NB)  // t3 partials: ZSPLIT slices

__device__ __forceinline__ float softplus_f(float x) {
    return fmaxf(x, 0.f) + __logf(1.f + __expf(-fabsf(x)));
}

// ---------------- Kernel 1: norms + t1 + t2 + zero out ----------------
__global__ __launch_bounds__(256) void prep_kernel(
    const float* __restrict__ pos, const float* __restrict__ neg,
    const float* __restrict__ w, float* __restrict__ ws, float* __restrict__ out)
{
    int gtid = blockIdx.x * 256 + threadIdx.x;
    if (gtid == 0) out[0] = 0.f;
    int row  = gtid >> 6;     // one wave per row, 1024 rows (allv order)
    int lane = threadIdx.x & 63;
    if (row >= NB) return;
    bool is_pos = row < NPOS;
    const float* r = is_pos ? pos + row * DIM : neg + (row - NPOS) * DIM;

    const float4* r4  = (const float4*)r + lane * 2;
    const float4* w14 = (const float4*)(w) + lane * 2;
    const float4* w24 = (const float4*)(w + DIM) + lane * 2;
    float4 a0 = r4[0],  a1 = r4[1];
    float4 u0 = w14[0], u1 = w14[1];
    float4 v0 = w24[0], v1 = w24[1];

    float ss  = a0.x*a0.x + a0.y*a0.y + a0.z*a0.z + a0.w*a0.w
              + a1.x*a1.x + a1.y*a1.y + a1.z*a1.z + a1.w*a1.w;
    float dw1 = a0.x*u0.x + a0.y*u0.y + a0.z*u0.z + a0.w*u0.w
              + a1.x*u1.x + a1.y*u1.y + a1.z*u1.z + a1.w*u1.w;
    float dw2 = a0.x*v0.x + a0.y*v0.y + a0.z*v0.z + a0.w*v0.w
              + a1.x*v1.x + a1.y*v1.y + a1.z*v1.z + a1.w*v1.w;

    #pragma unroll
    for (int off = 32; off; off >>= 1) {
        ss  += __shfl_xor(ss, off);
        dw1 += __shfl_xor(dw1, off);
        dw2 += __shfl_xor(dw2, off);
    }
    if (lane == 0) {
        float inv = 1.f / fmaxf(sqrtf(ss), COS_EPS);
        ws[OFF_INV + row] = inv;
        ws[OFF_T2 + row]  = dw2;
        if (is_pos) ws[OFF_T1 + row] = dw1;
    }
}

// ---------------- Kernel 2: fused cos + t3 partials ----------------
// 64n x 64m tile, 4x4 per thread (interleaved rows ti+16r, cols tj+16s),
// k-split(4) over grid z. grid (16,8,4) = 512 blocks -> 2 blocks/CU,
// 2 waves/SIMD so a co-resident block hides the other's staging stalls.
__global__ __launch_bounds__(256) void fused_kernel(
    const float* __restrict__ pos, const float* __restrict__ neg,
    const float* __restrict__ w, float* __restrict__ ws)
{
    __shared__ __align__(16) float As[64][36];
    __shared__ __align__(16) float Bs[64][36];

    const int tid = threadIdx.x;
    const int n0 = blockIdx.y * 64;
    const int m0 = blockIdx.x * 64;
    const int z  = blockIdx.z;
    const float* Asrc = pos + (size_t)n0 * DIM + z * KSLICE;
    const float* Bsrc = ((m0 < NPOS) ? (pos + (size_t)m0 * DIM)
                                     : (neg + (size_t)(m0 - NPOS) * DIM)) + z * KSLICE;
    const float* w3 = w + 2 * DIM + z * KSLICE;

    const int lr = tid >> 3;       // 0..31 staging row
    const int lc = (tid & 7) << 2; // 0..28 staging col
    const int ti = tid >> 4;       // 0..15
    const int tj = tid & 15;       // 0..15

    float c[4][4] = {{0.f}}, t[4][4] = {{0.f}};

    // prologue staging
    float4 a0 = *(const float4*)(Asrc + lr * DIM + lc);
    float4 a1 = *(const float4*)(Asrc + (lr + 32) * DIM + lc);
    float4 b0 = *(const float4*)(Bsrc + lr * DIM + lc);
    float4 b1 = *(const float4*)(Bsrc + (lr + 32) * DIM + lc);
    *(float4*)&As[lr][lc]      = a0;
    *(float4*)&As[lr + 32][lc] = a1;
    *(float4*)&Bs[lr][lc]      = b0;
    *(float4*)&Bs[lr + 32][lc] = b1;
    __syncthreads();

    #pragma unroll 1
    for (int iter = 0; iter < KSLICE / 32; ++iter) {
        const bool more = (iter < KSLICE / 32 - 1);
        if (more) {   // prefetch next tile into regs (hides global latency)
            const float* ap = Asrc + (iter + 1) * 32;
            const float* bp = Bsrc + (iter + 1) * 32;
            a0 = *(const float4*)(ap + lr * DIM + lc);
            a1 = *(const float4*)(ap + (lr + 32) * DIM + lc);
            b0 = *(const float4*)(bp + lr * DIM + lc);
            b1 = *(const float4*)(bp + (lr + 32) * DIM + lc);
        }
        const float* w3i = w3 + iter * 32;
        #pragma unroll
        for (int k = 0; k < 32; k += 4) {
            float4 av[4], bv[4];
            #pragma unroll
            for (int r = 0; r < 4; ++r) av[r] = *(const float4*)&As[ti + 16 * r][k];
            #pragma unroll
            for (int s = 0; s < 4; ++s) bv[s] = *(const float4*)&Bs[tj + 16 * s][k];
            const float4 wv = *(const float4*)(w3i + k);  // uniform -> s_load
            #pragma unroll
            for (int r = 0; r < 4; ++r) {
                #pragma unroll
                for (int s = 0; s < 4; ++s) {
                    c[r][s] = fmaf(av[r].x, bv[s].x, c[r][s]);
                    c[r][s] = fmaf(av[r].y, bv[s].y, c[r][s]);
                    c[r][s] = fmaf(av[r].z, bv[s].z, c[r][s]);
                    c[r][s] = fmaf(av[r].w, bv[s].w, c[r][s]);
                    t[r][s] = fmaf(fabsf(av[r].x - bv[s].x), wv.x, t[r][s]);
                    t[r][s] = fmaf(fabsf(av[r].y - bv[s].y), wv.y, t[r][s]);
                    t[r][s] = fmaf(fabsf(av[r].z - bv[s].z), wv.z, t[r][s]);
                    t[r][s] = fmaf(fabsf(av[r].w - bv[s].w), wv.w, t[r][s]);
                }
            }
        }
        if (more) {
            __syncthreads();
            *(float4*)&As[lr][lc]      = a0;
            *(float4*)&As[lr + 32][lc] = a1;
            *(float4*)&Bs[lr][lc]      = b0;
            *(float4*)&Bs[lr + 32][lc] = b1;
            __syncthreads();
        }
    }

    float* Sp = ws + OFF_P + (size_t)z * NPOS * NB;
    float* Tp = ws + OFF_Q + (size_t)z * NPOS * NB;
    #pragma unroll
    for (int r = 0; r < 4; ++r) {
        int n = n0 + ti + 16 * r;
        #pragma unroll
        for (int s = 0; s < 4; ++s) {
            int m = m0 + tj + 16 * s;
            Sp[(size_t)n * NB + m] = c[r][s];
            Tp[(size_t)n * NB + m] = t[r][s];
        }
    }
}

// ---------------- Kernel 3: combine partials + closs + BCE ----------------
// one wave per pos row n; 256 blocks x 128 threads (all 256 CUs covered).
__global__ __launch_bounds__(128) void finish_kernel(
    const float* __restrict__ lb, float* __restrict__ ws, float* __restrict__ out)
{
    const int n = blockIdx.x * 2 + (threadIdx.x >> 6);
    const int l = threadIdx.x & 63;
    const float4* S[ZSPLIT];
    const float4* T[ZSPLIT];
    #pragma unroll
    for (int zz = 0; zz < ZSPLIT; ++zz) {
        S[zz] = (const float4*)(ws + OFF_P + (size_t)zz * NPOS * NB + (size_t)n * NB);
        T[zz] = (const float4*)(ws + OFF_Q + (size_t)zz * NPOS * NB + (size_t)n * NB);
    }
    const float invn = ws[OFF_INV + n];
    const float t1n  = ws[OFF_T1 + n];
    const float bias = lb[0];

    // cols: m = 4*(l + 64j); j=0,1 -> pos (logit_p), j=2,3 -> neg (deno)
    float4 cj[4];
    float eneg = 0.f;
    #pragma unroll
    for (int j = 0; j < 4; ++j) {
        int i4 = l + 64 * j;
        float4 s0 = S[0][i4], s1 = S[1][i4], s2 = S[2][i4], s3 = S[3][i4];
        float4 inv4 = *(const float4*)(ws + OFF_INV + 4 * i4);
        float4 cc;
        cc.x = (s0.x + s1.x + s2.x + s3.x) * invn * inv4.x;
        cc.y = (s0.y + s1.y + s2.y + s3.y) * invn * inv4.y;
        cc.z = (s0.z + s1.z + s2.z + s3.z) * invn * inv4.z;
        cc.w = (s0.w + s1.w + s2.w + s3.w) * invn * inv4.w;
        cj[j] = cc;
        if (j >= 2)
            eneg += __expf(cc.x) + __expf(cc.y) + __expf(cc.z) + __expf(cc.w);
    }
    #pragma unroll
    for (int off = 32; off; off >>= 1) eneg += __shfl_xor(eneg, off);

    float part = 0.f;
    #pragma unroll
    for (int j = 0; j < 2; ++j) {
        float4 cc = cj[j];
        part += __logf(eneg + __expf(cc.x) + EPSV) - cc.x;
        part += __logf(eneg + __expf(cc.y) + EPSV) - cc.y;
        part += __logf(eneg + __expf(cc.z) + EPSV) - cc.z;
        part += __logf(eneg + __expf(cc.w) + EPSV) - cc.w;
    }

    float bce = 0.f;
    #pragma unroll
    for (int j = 0; j < 4; ++j) {
        int i4 = l + 64 * j;
        float4 t0 = T[0][i4], t1 = T[1][i4], t2_ = T[2][i4], t3_ = T[3][i4];
        float4 tw = *(const float4*)(ws + OFF_T2 + 4 * i4);
        float4 lg;
        lg.x = t1n + tw.x + t0.x + t1.x + t2_.x + t3_.x + bias;
        lg.y = t1n + tw.y + t0.y + t1.y + t2_.y + t3_.y + bias;
        lg.z = t1n + tw.z + t0.z + t1.z + t2_.z + t3_.z + bias;
        lg.w = t1n + tw.w + t0.w + t1.w + t2_.w + t3_.w + bias;
        if (j < 2)
            bce += softplus_f(-lg.x) + softplus_f(-lg.y) + softplus_f(-lg.z) + softplus_f(-lg.w);
        else
            bce += softplus_f(lg.x) + softplus_f(lg.y) + softplus_f(lg.z) + softplus_f(lg.w);
    }
    part += bce * (1.f / 1024.f);

    #pragma unroll
    for (int off = 32; off; off >>= 1) part += __shfl_xor(part, off);
    if (l == 0) atomicAdd(out, part);
}

extern "C" void kernel_launch(void* const* d_in, const int* in_sizes, int n_in,
                              void* d_out, int out_size, void* d_ws, size_t ws_size,
                              hipStream_t stream) {
    (void)in_sizes; (void)n_in; (void)out_size; (void)ws_size;
    const float* pos = (const float*)d_in[0];
    const float* neg = (const float*)d_in[1];
    const float* w   = (const float*)d_in[2];
    const float* lb  = (const float*)d_in[3];
    float* out = (float*)d_out;
    float* ws  = (float*)d_ws;

    prep_kernel<<<256, 256, 0, stream>>>(pos, neg, w, ws, out);
    fused_kernel<<<dim3(16, 8, ZSPLIT), 256, 0, stream>>>(pos, neg, w, ws);
    finish_kernel<<<256, 128, 0, stream>>>(lb, ws, out);
}

// Round 2
// 108.647 us; speedup vs baseline: 1.0113x; 1.0113x over previous
//
#include <hip/hip_runtime.h>
#include <math.h>

#define NPOS 512
#define DIM  512
#define NB   1024
#define EPSV 1e-5f
#define COS_EPS 1e-8f

// ws float offsets (total ~1.05 MB -> L2-resident)
#define OFF_INV  0                     // [1024] inv norms, allv order [pos;neg]
#define OFF_T1   1024                  // [512]  pos . w1
#define OFF_T2   1536                  // [1024] allv . w2
#define OFF_DENO 2560                  // [512]  sum_m(neg) exp(cos)
#define OFF_COS  3072                  // [512*512] cos(pos_n, pos_m)

__device__ __forceinline__ float softplus_f(float x) {
    return fmaxf(x, 0.f) + __logf(1.f + __expf(-fabsf(x)));
}

// ---------------- Kernel 1: norms + t1 + t2 + zero out/deno ----------------
__global__ __launch_bounds__(256) void prep_kernel(
    const float* __restrict__ pos, const float* __restrict__ neg,
    const float* __restrict__ w, float* __restrict__ ws, float* __restrict__ out)
{
    int gtid = blockIdx.x * 256 + threadIdx.x;
    if (gtid == 0) out[0] = 0.f;
    if (gtid < NPOS) ws[OFF_DENO + gtid] = 0.f;
    int row  = gtid >> 6;     // one wave per row, 1024 rows (allv order)
    int lane = threadIdx.x & 63;
    if (row >= NB) return;
    bool is_pos = row < NPOS;
    const float* r = is_pos ? pos + row * DIM : neg + (row - NPOS) * DIM;

    const float4* r4  = (const float4*)r + lane * 2;
    const float4* w14 = (const float4*)(w) + lane * 2;
    const float4* w24 = (const float4*)(w + DIM) + lane * 2;
    float4 a0 = r4[0],  a1 = r4[1];
    float4 u0 = w14[0], u1 = w14[1];
    float4 v0 = w24[0], v1 = w24[1];

    float ss  = a0.x*a0.x + a0.y*a0.y + a0.z*a0.z + a0.w*a0.w
              + a1.x*a1.x + a1.y*a1.y + a1.z*a1.z + a1.w*a1.w;
    float dw1 = a0.x*u0.x + a0.y*u0.y + a0.z*u0.z + a0.w*u0.w
              + a1.x*u1.x + a1.y*u1.y + a1.z*u1.z + a1.w*u1.w;
    float dw2 = a0.x*v0.x + a0.y*v0.y + a0.z*v0.z + a0.w*v0.w
              + a1.x*v1.x + a1.y*v1.y + a1.z*v1.z + a1.w*v1.w;

    #pragma unroll
    for (int off = 32; off; off >>= 1) {
        ss  += __shfl_xor(ss, off);
        dw1 += __shfl_xor(dw1, off);
        dw2 += __shfl_xor(dw2, off);
    }
    if (lane == 0) {
        float inv = 1.f / fmaxf(sqrtf(ss), COS_EPS);
        ws[OFF_INV + row] = inv;
        ws[OFF_T2 + row]  = dw2;
        if (is_pos) ws[OFF_T1 + row] = dw1;
    }
}

// ---------------- Kernel 2: fused cos + t3, full-k, in-kernel epilogue ----
// 32n x 64m tile, full k=512. grid (16,16) = 256 blocks = 1/CU.
// Per thread: 2x4 microtile (rows ti+16r, cols tj+16s).
// Epilogue: BCE softplus summed in-block -> atomicAdd(out);
//           neg cols: exp(cos) row-reduced -> atomicAdd(deno[n]);
//           pos cols: raw cos stored to 1MB buffer for finish.
__global__ __launch_bounds__(256) void fused_kernel(
    const float* __restrict__ pos, const float* __restrict__ neg,
    const float* __restrict__ w, const float* __restrict__ lb,
    float* __restrict__ ws, float* __restrict__ out)
{
    __shared__ __align__(16) float As[32][36];
    __shared__ __align__(16) float Bs[64][36];
    __shared__ float red[4];

    const int tid = threadIdx.x;
    const int n0 = blockIdx.y * 32;
    const int m0 = blockIdx.x * 64;
    const bool isneg = (m0 >= NPOS);
    const float* Asrc = pos + (size_t)n0 * DIM;
    const float* Bsrc = isneg ? (neg + (size_t)(m0 - NPOS) * DIM)
                              : (pos + (size_t)m0 * DIM);
    const float* w3 = w + 2 * DIM;

    const int lr = tid >> 3;       // 0..31 staging row
    const int lc = (tid & 7) << 2; // 0..28 staging col
    const int ti = tid >> 4;       // 0..15
    const int tj = tid & 15;       // 0..15

    float c[2][4] = {{0.f}}, t[2][4] = {{0.f}};

    // prologue staging (A: 1 float4/thread, B: 2 float4/thread)
    float4 a0 = *(const float4*)(Asrc + lr * DIM + lc);
    float4 b0 = *(const float4*)(Bsrc + lr * DIM + lc);
    float4 b1 = *(const float4*)(Bsrc + (lr + 32) * DIM + lc);
    *(float4*)&As[lr][lc]      = a0;
    *(float4*)&Bs[lr][lc]      = b0;
    *(float4*)&Bs[lr + 32][lc] = b1;
    __syncthreads();

    #pragma unroll 1
    for (int iter = 0; iter < DIM / 32; ++iter) {
        const bool more = (iter < DIM / 32 - 1);
        if (more) {   // register prefetch of next k-chunk
            const float* ap = Asrc + (iter + 1) * 32;
            const float* bp = Bsrc + (iter + 1) * 32;
            a0 = *(const float4*)(ap + lr * DIM + lc);
            b0 = *(const float4*)(bp + lr * DIM + lc);
            b1 = *(const float4*)(bp + (lr + 32) * DIM + lc);
        }
        const float* w3i = w3 + iter * 32;
        #pragma unroll
        for (int k = 0; k < 32; k += 4) {
            float4 av[2], bv[4];
            #pragma unroll
            for (int r = 0; r < 2; ++r) av[r] = *(const float4*)&As[ti + 16 * r][k];
            #pragma unroll
            for (int s = 0; s < 4; ++s) bv[s] = *(const float4*)&Bs[tj + 16 * s][k];
            const float4 wv = *(const float4*)(w3i + k);  // uniform -> s_load
            #pragma unroll
            for (int r = 0; r < 2; ++r) {
                #pragma unroll
                for (int s = 0; s < 4; ++s) {
                    c[r][s] = fmaf(av[r].x, bv[s].x, c[r][s]);
                    c[r][s] = fmaf(av[r].y, bv[s].y, c[r][s]);
                    c[r][s] = fmaf(av[r].z, bv[s].z, c[r][s]);
                    c[r][s] = fmaf(av[r].w, bv[s].w, c[r][s]);
                    t[r][s] = fmaf(fabsf(av[r].x - bv[s].x), wv.x, t[r][s]);
                    t[r][s] = fmaf(fabsf(av[r].y - bv[s].y), wv.y, t[r][s]);
                    t[r][s] = fmaf(fabsf(av[r].z - bv[s].z), wv.z, t[r][s]);
                    t[r][s] = fmaf(fabsf(av[r].w - bv[s].w), wv.w, t[r][s]);
                }
            }
        }
        if (more) {
            __syncthreads();
            *(float4*)&As[lr][lc]      = a0;
            *(float4*)&Bs[lr][lc]      = b0;
            *(float4*)&Bs[lr + 32][lc] = b1;
            __syncthreads();
        }
    }

    // ---- epilogue ----
    const float bias = lb[0];
    float inv_n[2], t1_n[2], inv_m[4], t2_m[4];
    #pragma unroll
    for (int r = 0; r < 2; ++r) {
        int n = n0 + ti + 16 * r;
        inv_n[r] = ws[OFF_INV + n];
        t1_n[r]  = ws[OFF_T1 + n];
    }
    #pragma unroll
    for (int s = 0; s < 4; ++s) {
        int m = m0 + tj + 16 * s;      // allv index
        inv_m[s] = ws[OFF_INV + m];
        t2_m[s]  = ws[OFF_T2 + m];
    }

    float bce = 0.f;
    float rowsum[2] = {0.f, 0.f};
    #pragma unroll
    for (int r = 0; r < 2; ++r) {
        #pragma unroll
        for (int s = 0; s < 4; ++s) {
            float cc = c[r][s] * inv_n[r] * inv_m[s];
            float lg = t1_n[r] + t2_m[s] + t[r][s] + bias;
            bce += softplus_f(isneg ? lg : -lg);
            if (isneg) {
                rowsum[r] += __expf(cc);
            } else {
                int n = n0 + ti + 16 * r;
                int m = m0 + tj + 16 * s;   // < NPOS here
                ws[OFF_COS + (size_t)n * NPOS + m] = cc;
            }
        }
    }

    if (isneg) {
        // reduce over the 16-lane tj group (same ti) -> full 64-col row sum
        #pragma unroll
        for (int off = 1; off < 16; off <<= 1) {
            rowsum[0] += __shfl_xor(rowsum[0], off);
            rowsum[1] += __shfl_xor(rowsum[1], off);
        }
        if (tj == 0) {
            atomicAdd(&ws[OFF_DENO + n0 + ti], rowsum[0]);
            atomicAdd(&ws[OFF_DENO + n0 + ti + 16], rowsum[1]);
        }
    }

    // block-reduce BCE -> single atomic
    #pragma unroll
    for (int off = 32; off; off >>= 1) bce += __shfl_xor(bce, off);
    const int lane = tid & 63, wid = tid >> 6;
    if (lane == 0) red[wid] = bce;
    __syncthreads();
    if (tid == 0)
        atomicAdd(out, (red[0] + red[1] + red[2] + red[3]) * (1.f / 1024.f));
}

// ---------------- Kernel 3: closs from deno + stored cos ----------------
// one wave per pos row n; 256 blocks x 128 threads.
__global__ __launch_bounds__(128) void finish_kernel(
    float* __restrict__ ws, float* __restrict__ out)
{
    const int n = blockIdx.x * 2 + (threadIdx.x >> 6);
    const int l = threadIdx.x & 63;
    const float4* C = (const float4*)(ws + OFF_COS + (size_t)n * NPOS);
    const float deno = ws[OFF_DENO + n];

    float part = 0.f;
    #pragma unroll
    for (int j = 0; j < 2; ++j) {
        float4 cc = C[l + 64 * j];
        part += __logf(deno + __expf(cc.x) + EPSV) - cc.x;
        part += __logf(deno + __expf(cc.y) + EPSV) - cc.y;
        part += __logf(deno + __expf(cc.z) + EPSV) - cc.z;
        part += __logf(deno + __expf(cc.w) + EPSV) - cc.w;
    }

    #pragma unroll
    for (int off = 32; off; off >>= 1) part += __shfl_xor(part, off);
    if (l == 0) atomicAdd(out, part);
}

extern "C" void kernel_launch(void* const* d_in, const int* in_sizes, int n_in,
                              void* d_out, int out_size, void* d_ws, size_t ws_size,
                              hipStream_t stream) {
    (void)in_sizes; (void)n_in; (void)out_size; (void)ws_size;
    const float* pos = (const float*)d_in[0];
    const float* neg = (const float*)d_in[1];
    const float* w   = (const float*)d_in[2];
    const float* lb  = (const float*)d_in[3];
    float* out = (float*)d_out;
    float* ws  = (float*)d_ws;

    prep_kernel<<<256, 256, 0, stream>>>(pos, neg, w, ws, out);
    fused_kernel<<<dim3(16, 16), 256, 0, stream>>>(pos, neg, w, lb, ws, out);
    finish_kernel<<<256, 128, 0, stream>>>(ws, out);
}

// Round 3
// 98.983 us; speedup vs baseline: 1.1100x; 1.0976x over previous
//
#include <hip/hip_runtime.h>
#include <math.h>

#define NPOS 512
#define DIM  512
#define NB   1024
#define EPSV 1e-5f
#define COS_EPS 1e-8f

// ws float offsets (total ~1.05 MB -> L2-resident)
#define OFF_INV  0                     // [1024] inv norms, allv order [pos;neg]
#define OFF_T1   1024                  // [512]  pos . w1
#define OFF_T2   1536                  // [1024] allv . w2
#define OFF_DENO 2560                  // [512]  sum_m(neg) exp(cos)
#define OFF_COS  3072                  // [512*512] cos(pos_n, pos_m)

__device__ __forceinline__ float softplus_f(float x) {
    return fmaxf(x, 0.f) + __logf(1.f + __expf(-fabsf(x)));
}

// ---------------- Kernel 1: norms + t1 + t2 + zero out/deno ----------------
__global__ __launch_bounds__(256) void prep_kernel(
    const float* __restrict__ pos, const float* __restrict__ neg,
    const float* __restrict__ w, float* __restrict__ ws, float* __restrict__ out)
{
    int gtid = blockIdx.x * 256 + threadIdx.x;
    if (gtid == 0) out[0] = 0.f;
    if (gtid < NPOS) ws[OFF_DENO + gtid] = 0.f;
    int row  = gtid >> 6;     // one wave per row, 1024 rows (allv order)
    int lane = threadIdx.x & 63;
    if (row >= NB) return;
    bool is_pos = row < NPOS;
    const float* r = is_pos ? pos + row * DIM : neg + (row - NPOS) * DIM;

    const float4* r4  = (const float4*)r + lane * 2;
    const float4* w14 = (const float4*)(w) + lane * 2;
    const float4* w24 = (const float4*)(w + DIM) + lane * 2;
    float4 a0 = r4[0],  a1 = r4[1];
    float4 u0 = w14[0], u1 = w14[1];
    float4 v0 = w24[0], v1 = w24[1];

    float ss  = a0.x*a0.x + a0.y*a0.y + a0.z*a0.z + a0.w*a0.w
              + a1.x*a1.x + a1.y*a1.y + a1.z*a1.z + a1.w*a1.w;
    float dw1 = a0.x*u0.x + a0.y*u0.y + a0.z*u0.z + a0.w*u0.w
              + a1.x*u1.x + a1.y*u1.y + a1.z*u1.z + a1.w*u1.w;
    float dw2 = a0.x*v0.x + a0.y*v0.y + a0.z*v0.z + a0.w*v0.w
              + a1.x*v1.x + a1.y*v1.y + a1.z*v1.z + a1.w*v1.w;

    #pragma unroll
    for (int off = 32; off; off >>= 1) {
        ss  += __shfl_xor(ss, off);
        dw1 += __shfl_xor(dw1, off);
        dw2 += __shfl_xor(dw2, off);
    }
    if (lane == 0) {
        float inv = 1.f / fmaxf(sqrtf(ss), COS_EPS);
        ws[OFF_INV + row] = inv;
        ws[OFF_T2 + row]  = dw2;
        if (is_pos) ws[OFF_T1 + row] = dw1;
    }
}

// ---------------- Kernel 2: fused cos + t3, full-k, in-kernel epilogue ----
// 32n x 32m tile, full k=512. grid (32,16) = 512 blocks = 2 blocks/CU
// = 2 waves/SIMD: independent co-resident blocks hide each other's
// staging/barrier stalls. Double-buffered LDS -> 1 barrier per k-chunk.
// Per thread: 2x2 microtile (rows ti+16r, cols tj+16s).
__global__ __launch_bounds__(256) void fused_kernel(
    const float* __restrict__ pos, const float* __restrict__ neg,
    const float* __restrict__ w, const float* __restrict__ lb,
    float* __restrict__ ws, float* __restrict__ out)
{
    __shared__ __align__(16) float As[2][32][36];
    __shared__ __align__(16) float Bs[2][32][36];
    __shared__ float red[4];

    const int tid = threadIdx.x;
    const int n0 = blockIdx.y * 32;
    const int m0 = blockIdx.x * 32;
    const bool isneg = (m0 >= NPOS);
    const float* Asrc = pos + (size_t)n0 * DIM;
    const float* Bsrc = isneg ? (neg + (size_t)(m0 - NPOS) * DIM)
                              : (pos + (size_t)m0 * DIM);
    const float* w3 = w + 2 * DIM;

    const int lr = tid >> 3;       // 0..31 staging row
    const int lc = (tid & 7) << 2; // 0..28 staging col
    const int ti = tid >> 4;       // 0..15
    const int tj = tid & 15;       // 0..15

    float c[2][2] = {{0.f}}, t[2][2] = {{0.f}};

    // prologue staging (1 float4/thread per matrix)
    float4 a0 = *(const float4*)(Asrc + lr * DIM + lc);
    float4 b0 = *(const float4*)(Bsrc + lr * DIM + lc);
    *(float4*)&As[0][lr][lc] = a0;
    *(float4*)&Bs[0][lr][lc] = b0;
    __syncthreads();

    #pragma unroll 1
    for (int iter = 0; iter < DIM / 32; ++iter) {
        const int cur = iter & 1;
        const bool more = (iter < DIM / 32 - 1);
        if (more) {   // register prefetch of next k-chunk (hides L2 latency)
            const float* ap = Asrc + (iter + 1) * 32;
            const float* bp = Bsrc + (iter + 1) * 32;
            a0 = *(const float4*)(ap + lr * DIM + lc);
            b0 = *(const float4*)(bp + lr * DIM + lc);
        }
        const float* w3i = w3 + iter * 32;
        #pragma unroll
        for (int k = 0; k < 32; k += 4) {
            float4 av0 = *(const float4*)&As[cur][ti][k];
            float4 av1 = *(const float4*)&As[cur][ti + 16][k];
            float4 bv0 = *(const float4*)&Bs[cur][tj][k];
            float4 bv1 = *(const float4*)&Bs[cur][tj + 16][k];
            const float4 wv = *(const float4*)(w3i + k);  // uniform -> s_load
            #define ACC(r, s, AV, BV) \
                c[r][s] = fmaf(AV.x, BV.x, c[r][s]); \
                c[r][s] = fmaf(AV.y, BV.y, c[r][s]); \
                c[r][s] = fmaf(AV.z, BV.z, c[r][s]); \
                c[r][s] = fmaf(AV.w, BV.w, c[r][s]); \
                t[r][s] = fmaf(fabsf(AV.x - BV.x), wv.x, t[r][s]); \
                t[r][s] = fmaf(fabsf(AV.y - BV.y), wv.y, t[r][s]); \
                t[r][s] = fmaf(fabsf(AV.z - BV.z), wv.z, t[r][s]); \
                t[r][s] = fmaf(fabsf(AV.w - BV.w), wv.w, t[r][s]);
            ACC(0, 0, av0, bv0)
            ACC(0, 1, av0, bv1)
            ACC(1, 0, av1, bv0)
            ACC(1, 1, av1, bv1)
            #undef ACC
        }
        if (more) {
            // write NEXT buffer (no read/write overlap), single barrier
            *(float4*)&As[cur ^ 1][lr][lc] = a0;
            *(float4*)&Bs[cur ^ 1][lr][lc] = b0;
            __syncthreads();
        }
    }

    // ---- epilogue ----
    const float bias = lb[0];
    float inv_n[2], t1_n[2], inv_m[2], t2_m[2];
    #pragma unroll
    for (int r = 0; r < 2; ++r) {
        int n = n0 + ti + 16 * r;
        inv_n[r] = ws[OFF_INV + n];
        t1_n[r]  = ws[OFF_T1 + n];
    }
    #pragma unroll
    for (int s = 0; s < 2; ++s) {
        int m = m0 + tj + 16 * s;      // allv index
        inv_m[s] = ws[OFF_INV + m];
        t2_m[s]  = ws[OFF_T2 + m];
    }

    float bce = 0.f;
    float rowsum[2] = {0.f, 0.f};
    #pragma unroll
    for (int r = 0; r < 2; ++r) {
        #pragma unroll
        for (int s = 0; s < 2; ++s) {
            float cc = c[r][s] * inv_n[r] * inv_m[s];
            float lg = t1_n[r] + t2_m[s] + t[r][s] + bias;
            bce += softplus_f(isneg ? lg : -lg);
            if (isneg) {
                rowsum[r] += __expf(cc);
            } else {
                int n = n0 + ti + 16 * r;
                int m = m0 + tj + 16 * s;   // < NPOS here
                ws[OFF_COS + (size_t)n * NPOS + m] = cc;
            }
        }
    }

    if (isneg) {
        // reduce over the 16-lane tj group (same ti) -> 32-col row sum
        #pragma unroll
        for (int off = 1; off < 16; off <<= 1) {
            rowsum[0] += __shfl_xor(rowsum[0], off);
            rowsum[1] += __shfl_xor(rowsum[1], off);
        }
        if (tj == 0) {
            atomicAdd(&ws[OFF_DENO + n0 + ti], rowsum[0]);
            atomicAdd(&ws[OFF_DENO + n0 + ti + 16], rowsum[1]);
        }
    }

    // block-reduce BCE -> single atomic
    #pragma unroll
    for (int off = 32; off; off >>= 1) bce += __shfl_xor(bce, off);
    const int lane = tid & 63, wid = tid >> 6;
    if (lane == 0) red[wid] = bce;
    __syncthreads();
    if (tid == 0)
        atomicAdd(out, (red[0] + red[1] + red[2] + red[3]) * (1.f / 1024.f));
}

// ---------------- Kernel 3: closs from deno + stored cos ----------------
// one wave per pos row n; 256 blocks x 128 threads.
__global__ __launch_bounds__(128) void finish_kernel(
    float* __restrict__ ws, float* __restrict__ out)
{
    const int n = blockIdx.x * 2 + (threadIdx.x >> 6);
    const int l = threadIdx.x & 63;
    const float4* C = (const float4*)(ws + OFF_COS + (size_t)n * NPOS);
    const float deno = ws[OFF_DENO + n];

    float part = 0.f;
    #pragma unroll
    for (int j = 0; j < 2; ++j) {
        float4 cc = C[l + 64 * j];
        part += __logf(deno + __expf(cc.x) + EPSV) - cc.x;
        part += __logf(deno + __expf(cc.y) + EPSV) - cc.y;
        part += __logf(deno + __expf(cc.z) + EPSV) - cc.z;
        part += __logf(deno + __expf(cc.w) + EPSV) - cc.w;
    }

    #pragma unroll
    for (int off = 32; off; off >>= 1) part += __shfl_xor(part, off);
    if (l == 0) atomicAdd(out, part);
}

extern "C" void kernel_launch(void* const* d_in, const int* in_sizes, int n_in,
                              void* d_out, int out_size, void* d_ws, size_t ws_size,
                              hipStream_t stream) {
    (void)in_sizes; (void)n_in; (void)out_size; (void)ws_size;
    const float* pos = (const float*)d_in[0];
    const float* neg = (const float*)d_in[1];
    const float* w   = (const float*)d_in[2];
    const float* lb  = (const float*)d_in[3];
    float* out = (float*)d_out;
    float* ws  = (float*)d_ws;

    prep_kernel<<<256, 256, 0, stream>>>(pos, neg, w, ws, out);
    fused_kernel<<<dim3(32, 16), 256, 0, stream>>>(pos, neg, w, lb, ws, out);
    finish_kernel<<<256, 128, 0, stream>>>(ws, out);
}